// Round 1
// baseline (120.970 us; speedup 1.0000x reference)
//
#include <hip/hip_runtime.h>
#include <hip/hip_bf16.h>
#include <stdint.h>

typedef unsigned short ushort_t;
typedef unsigned long long u64;
typedef __attribute__((ext_vector_type(8))) short short8;   // 8 bf16 (4 VGPRs)
typedef __attribute__((ext_vector_type(4))) float f32x4;

#define N_NODES 384
#define HF      512
#define IT      12        // i-rows per attention block: 32 tiles x 8 heads = 256

__device__ inline ushort_t f2bf(float f) {
  __hip_bfloat16 b = __float2bfloat16(f);
  return *reinterpret_cast<ushort_t*>(&b);
}
__device__ inline float bf2f_u(ushort_t u) {
  union { float f; uint32_t i; } v; v.i = ((uint32_t)u) << 16; return v.f;
}
__device__ inline short8 pack8(const float* s) {
  short8 r;
#pragma unroll
  for (int j = 0; j < 8; ++j) r[j] = (short)f2bf(s[j]);
  return r;
}

// ---------------------------------------------------------------------------
// Kernel 0: one-time pre-pack (R13). W[k][n] fp32 -> Wp[n][k] bf16 (k-contig,
// so gemm B-fragments become single short8 loads), for both layers; X fp32 ->
// Xbf bf16. Removes 24x-duplicated in-register W conversion from gemm_direct
// and its 256 scalar loads/wave.
// bid < 512: W pack (2 layers x 1024 n x 64 k-chunks). Reads coalesced along
// n (256 B/instr); 16-B scattered writes absorbed by L2 (2 MB total).
// bid >= 512: X pack, fully coalesced both sides.
// ---------------------------------------------------------------------------
__global__ __launch_bounds__(256) void prepack(
    const float* __restrict__ X,
    const float* __restrict__ Wl0, const float* __restrict__ Wr0,
    const float* __restrict__ Wl1, const float* __restrict__ Wr1,
    ushort_t* __restrict__ Xbf, ushort_t* __restrict__ Wp0,
    ushort_t* __restrict__ Wp1)
{
  const int bid = blockIdx.x, t = threadIdx.x;
  if (bid < 512) {
    int gid = bid * 256 + t;           // [0, 131072)
    int l   = gid >> 16;               // layer
    int r   = gid & 65535;
    int n   = r & 1023, kc = r >> 10;  // n fastest -> coalesced reads
    const float* Wsrc = (n < 512) ? (l ? Wl1 : Wl0) : (l ? Wr1 : Wr0);
    const int nn = n & 511;
    float v[8];
#pragma unroll
    for (int j = 0; j < 8; ++j) v[j] = Wsrc[(kc * 8 + j) * 512 + nn];
    ushort_t* dst = (l ? Wp1 : Wp0) + n * 512 + kc * 8;
    *(short8*)dst = pack8(v);
  } else {
    int gid = (bid - 512) * 256 + t;   // [0, 24576)
    const float* src = X + gid * 8;
    float4 a0 = *(const float4*)src, a1 = *(const float4*)(src + 4);
    float v[8] = {a0.x, a0.y, a0.z, a0.w, a1.x, a1.y, a1.z, a1.w};
    *(short8*)(Xbf + gid * 8) = pack8(v);
  }
}

// ---------------------------------------------------------------------------
// Kernel 1/3: dual GEMM (R13: pre-packed bf16 operands). Per kc the wave now
// issues 3 x short8 vector loads + 2 MFMA instead of 2 float4 + 16 scalar
// loads + 3 pack8 (~36 cvt). Same (24,8)/32n-per-wave shape as R10 (R8+R12
// showed the 16n/384-block variant is ~+3 us/launch worse).
// G[m][n] = sum_k X[m][k]*W[k][n], n in [0,1024), Wp = [WL | WR] bf16 [n][k].
//  n <  512 (gl): glb bf16 [m][n]
//  n >= 512 (gr): G fp32 [m][512+n'] and grT bf16 [n'][m] (k-contig)
// grid (24, 8), 256 threads = 4 waves; wave computes 16m x 32n.
// Layer 0 extra: adjacency bitmasks (by==0 blocks).
// ---------------------------------------------------------------------------
__global__ __launch_bounds__(256) void gemm_direct(
    const ushort_t* __restrict__ Xbf, const ushort_t* __restrict__ Wp,
    float* __restrict__ G,
    ushort_t* __restrict__ glb, ushort_t* __restrict__ grT,
    const int* __restrict__ adj, u64* __restrict__ mbits)
{
  const int t = threadIdx.x, wave = t >> 6, lane = t & 63;
  const int lm = lane & 15, q = lane >> 4;
  const int m0 = blockIdx.x * 16;
  const int n0 = (blockIdx.y * 4 + wave) * 32;
  const ushort_t* Arow  = Xbf + (m0 + lm) * 512;
  const ushort_t* Brow0 = Wp + (n0 + lm) * 512;
  const ushort_t* Brow1 = Wp + (n0 + 16 + lm) * 512;

  f32x4 acc0 = {0.f, 0.f, 0.f, 0.f};
  f32x4 acc1 = {0.f, 0.f, 0.f, 0.f};
#pragma unroll
  for (int kc = 0; kc < 16; ++kc) {
    const int kbase = kc * 32 + q * 8;
    short8 af = *(const short8*)(Arow + kbase);
    short8 b0 = *(const short8*)(Brow0 + kbase);
    short8 b1 = *(const short8*)(Brow1 + kbase);
    acc0 = __builtin_amdgcn_mfma_f32_16x16x32_bf16(af, b0, acc0, 0, 0, 0);
    acc1 = __builtin_amdgcn_mfma_f32_16x16x32_bf16(af, b1, acc1, 0, 0, 0);
  }
  if (n0 < 512) {
#pragma unroll
    for (int r = 0; r < 4; ++r) {
      int m = m0 + q * 4 + r;
      glb[m * HF + n0 + lm]      = f2bf(acc0[r]);
      glb[m * HF + n0 + 16 + lm] = f2bf(acc1[r]);
    }
  } else {
#pragma unroll
    for (int r = 0; r < 4; ++r) {
      int m = m0 + q * 4 + r;
      G[m * 1024 + n0 + lm]      = acc0[r];
      G[m * 1024 + n0 + 16 + lm] = acc1[r];
    }
    int c0 = n0 - 512;
    uint2 p0, p1;
    p0.x = (uint32_t)f2bf(acc0[0]) | ((uint32_t)f2bf(acc0[1]) << 16);
    p0.y = (uint32_t)f2bf(acc0[2]) | ((uint32_t)f2bf(acc0[3]) << 16);
    p1.x = (uint32_t)f2bf(acc1[0]) | ((uint32_t)f2bf(acc1[1]) << 16);
    p1.y = (uint32_t)f2bf(acc1[2]) | ((uint32_t)f2bf(acc1[3]) << 16);
    *(uint2*)&grT[(c0 + lm) * 384 + m0 + q * 4]      = p0;
    *(uint2*)&grT[(c0 + 16 + lm) * 384 + m0 + q * 4] = p1;
  }
  // layer-0 only: adjacency bitmasks (self-loop OR'd in), by==0 blocks
  if (adj != nullptr && blockIdx.y == 0) {
    int rbase = (blockIdx.x * 4 + wave) * 4;
    for (int rr = 0; rr < 4; ++rr) {
      int row = rbase + rr;
#pragma unroll
      for (int w = 0; w < 6; ++w) {
        int j = w * 64 + lane;
        u64 m = __ballot(adj[row * N_NODES + j] != 0 || row == j);
        if (lane == 0) mbits[row * 6 + w] = m;
      }
    }
  }
}

// ---------------------------------------------------------------------------
// Kernel 2/4: fused GATv2 attention (R10 + 3-barrier restructure, unchanged
// except LAYER==0 epilogue also emits bf16 xcur so gemm1's A-loads are
// vector bf16).
// Block = (12-row i-tile, head), 384 thr, grid (32,8) = 256 blocks = 1/CU.
// LDS ~80.6 KB -> 1 block/CU.
// ---------------------------------------------------------------------------
template <int LAYER>
__global__ __launch_bounds__(384) void attn_fused(
    const float* __restrict__ G, const ushort_t* __restrict__ glb,
    const ushort_t* __restrict__ grT, const u64* __restrict__ mbits,
    const float* __restrict__ resid_in, const float* __restrict__ avec,
    float* __restrict__ xcur_out, ushort_t* __restrict__ xbf_out,
    float* __restrict__ f_out)
{
  __shared__ __align__(16) char smem[49152];          // s_gl (DMA dst only)
  __shared__ float    s_e[IT][N_NODES];               // 18432 B (separate!)
  __shared__ ushort_t s_pb[16][392];                  // 12544 B
  __shared__ float s_bri[IT];
  __shared__ u64   s_mask[IT][6];
  ushort_t (*s_gl)[64] = (ushort_t(*)[64])smem;

  const int t = threadIdx.x;
  const int i0 = blockIdx.x * IT, h = blockIdx.y;
  const int lane = t & 63, wave = t >> 6;
  const int lm = lane & 15, q = lane >> 4;

  // -- issue async global->LDS DMA first (8 x 16 B per thread) --
#pragma unroll
  for (int rep = 0; rep < 8; ++rep) {
    int idx = rep * 384 + t, row = idx >> 3, cl = idx & 7;
    int cg = cl ^ (row & 7);
    const ushort_t* gsrc = glb + row * HF + h * 64 + cg * 8;
    __builtin_amdgcn_global_load_lds(
        (const __attribute__((address_space(1))) uint32_t*)gsrc,
        (__attribute__((address_space(3))) uint32_t*)(smem + idx * 16),
        16, 0, 0);
  }

  // -- prefetch phase-3 B-fragments + epilogue resid (independent loads) --
  short8 bfrag[12];
  float  rres[4];
  if (wave < 4) {
    const ushort_t* Brow = grT + (h * 64 + wave * 16 + lm) * 384;
#pragma unroll
    for (int kc = 0; kc < 12; ++kc)
      bfrag[kc] = *(const short8*)&Brow[kc * 32 + q * 8];
    if (q < 3) {
#pragma unroll
      for (int r = 0; r < 4; ++r)
        rres[r] = resid_in[(i0 + q * 4 + r) * HF + h * 64 + wave * 16 + lm];
    }
  }

  // -- overlapped with DMA: masks (72 u64) + bri dot + s_pb pad zeroing --
  if (t < 72) ((u64*)s_mask)[t] = mbits[i0 * 6 + t];
  if (t >= 128 && t < 320) {
    int u = t - 128, il = u >> 4, fg = u & 15;
    float4 g4 = *(const float4*)(G + (i0 + il) * 1024 + 512 + h * 64 + fg * 4);
    float4 a4 = *(const float4*)(avec + fg * 4);
    float s = a4.x * g4.x + a4.y * g4.y + a4.z * g4.z + a4.w * g4.w;
    s += __shfl_xor(s, 1); s += __shfl_xor(s, 2);
    s += __shfl_xor(s, 4); s += __shfl_xor(s, 8);
    if (fg == 0) s_bri[il] = s;
  }
#pragma unroll
  for (int r4 = 0; r4 < 4; ++r4) s_pb[IT + r4][t] = 0;  // zero P rows 12..15
  __syncthreads();   // barrier 1: drains DMA + overlap work

  // -- own j-row -> 64 VGPRs (chunk cg at slot cg^(t&7)); avec -> VGPRs --
  float gl[64], av[64];
  {
    const int sw = t & 7;
#pragma unroll
    for (int cg = 0; cg < 8; ++cg) {
      short8 v = *(const short8*)&s_gl[t][(cg ^ sw) * 8];
#pragma unroll
      for (int u2 = 0; u2 < 8; ++u2)
        gl[cg * 8 + u2] = bf2f_u((ushort_t)v[u2]);
    }
#pragma unroll
    for (int c = 0; c < 16; ++c) {
      float4 a4 = ((const float4*)avec)[c];
      av[c * 4] = a4.x; av[c * 4 + 1] = a4.y;
      av[c * 4 + 2] = a4.z; av[c * 4 + 3] = a4.w;
    }
  }
  float accl = 0.f;
#pragma unroll
  for (int f = 0; f < 64; ++f) accl += av[f] * gl[f];
  // no barrier: s_e is a separate region; each thread writes its own column

  // -- phase 1: scores, written straight to LDS --
  const int jw = t >> 6, jb = t & 63;
#pragma unroll
  for (int il = 0; il < IT; ++il) {
    const float4* gr4 = (const float4*)(G + (i0 + il) * 1024 + 512 + h * 64);
    float acc = 0.f;
#pragma unroll
    for (int c = 0; c < 16; ++c) {
      float4 g4 = gr4[c];
      acc += av[c * 4]     * fabsf(gl[c * 4]     + g4.x);
      acc += av[c * 4 + 1] * fabsf(gl[c * 4 + 1] + g4.y);
      acc += av[c * 4 + 2] * fabsf(gl[c * 4 + 2] + g4.z);
      acc += av[c * 4 + 3] * fabsf(gl[c * 4 + 3] + g4.w);
    }
    bool m = (s_mask[il][jw] >> jb) & 1;
    float e = 0.6f * (accl + s_bri[il]) + 0.4f * acc;
    s_e[il][t] = m ? e : -1e30f;
  }
  __syncthreads();   // barrier 2: scores visible to softmax waves

  // -- phase 2: softmax over j per row; write normalized P bf16 --
#pragma unroll
  for (int rep = 0; rep < 2; ++rep) {
    int il = wave * 2 + rep;
    float v[6];
    float mx = -1e30f;
#pragma unroll
    for (int c = 0; c < 6; ++c) { v[c] = s_e[il][lane + 64 * c]; mx = fmaxf(mx, v[c]); }
#pragma unroll
    for (int off = 32; off; off >>= 1) mx = fmaxf(mx, __shfl_xor(mx, off));
    float sum = 0.f;
#pragma unroll
    for (int c = 0; c < 6; ++c) { v[c] = __expf(v[c] - mx); sum += v[c]; }
#pragma unroll
    for (int off = 32; off; off >>= 1) sum += __shfl_xor(sum, off);
    float inv = 1.0f / sum;
#pragma unroll
    for (int c = 0; c < 6; ++c) s_pb[il][lane + 64 * c] = f2bf(v[c] * inv);
  }
  __syncthreads();   // barrier 3: P visible to MFMA waves

  // -- phase 3: MFMA (A from LDS, B + resid already in registers) --
  if (wave < 4) {
    f32x4 acc = {0.f, 0.f, 0.f, 0.f};
#pragma unroll
    for (int kc = 0; kc < 12; ++kc) {
      short8 af = *(const short8*)&s_pb[lm][kc * 32 + q * 8];
      acc = __builtin_amdgcn_mfma_f32_16x16x32_bf16(af, bfrag[kc], acc, 0, 0, 0);
    }
    if (q < 3) {                                    // D rows 0..11
#pragma unroll
      for (int r = 0; r < 4; ++r) {
        int i = i0 + q * 4 + r;
        int off = i * HF + h * 64 + wave * 16 + lm;
        float o = acc[r];
        if (LAYER == 0) {
          float oe = (o > 0.f) ? o : (__expf(o) - 1.f);   // ELU
          float v = rres[r] + oe;
          xcur_out[off] = v;            // fp32 residual for layer-1 epilogue
          xbf_out[off]  = f2bf(v);      // bf16 A-operand for layer-1 gemm
        } else {
          f_out[off] = rres[r] + o;       // final output, fp32
        }
      }
    }
  }
}

// ---------------------------------------------------------------------------
extern "C" void kernel_launch(void* const* d_in, const int* in_sizes, int n_in,
                              void* d_out, int out_size, void* d_ws, size_t ws_size,
                              hipStream_t stream) {
  const float* x   = (const float*)d_in[0];
  const int*   adj = (const int*)d_in[1];
  const float* Wl0 = (const float*)d_in[2];
  const float* Wr0 = (const float*)d_in[3];
  const float* a0  = (const float*)d_in[4];
  const float* Wl1 = (const float*)d_in[5];
  const float* Wr1 = (const float*)d_in[6];
  const float* a1  = (const float*)d_in[7];
  float* out = (float*)d_out;

  char* ws = (char*)d_ws;
  float*    G    = (float*)   (ws + 0L);            // 1.5 MB (gr half used)
  ushort_t* grT  = (ushort_t*)(ws + (2L << 20));    // 384 KB gr^T bf16
  ushort_t* glb  = (ushort_t*)(ws + (3L << 20));    // 384 KB gl bf16
  u64*      mbits= (u64*)     (ws + (4L << 20));    // 18 KB adjacency bits
  float*    xcur = (float*)   (ws + (5L << 20));    // 768 KB fp32 residual
  ushort_t* Xbf0 = (ushort_t*)(ws + (6L << 20));    // 384 KB bf16 X (layer 0)
  ushort_t* xbfc = (ushort_t*)(ws + (7L << 20));    // 384 KB bf16 xcur
  ushort_t* Wp0  = (ushort_t*)(ws + (8L << 20));    // 1 MB bf16 [WL0|WR0]^T(k)
  ushort_t* Wp1  = (ushort_t*)(ws + (9L << 20));    // 1 MB bf16 [WL1|WR1]^T(k)

  prepack<<<608, 256, 0, stream>>>(x, Wl0, Wr0, Wl1, Wr1, Xbf0, Wp0, Wp1);
  gemm_direct<<<dim3(24, 8), 256, 0, stream>>>(Xbf0, Wp0, G, glb, grT,
                                               adj, mbits);
  attn_fused<0><<<dim3(32, 8), 384, 0, stream>>>(G, glb, grT, mbits, x, a0,
                                                 xcur, xbfc, nullptr);
  gemm_direct<<<dim3(24, 8), 256, 0, stream>>>(xbfc, Wp1, G, glb, grT,
                                               nullptr, nullptr);
  attn_fused<1><<<dim3(32, 8), 384, 0, stream>>>(G, glb, grT, mbits, xcur, a1,
                                                 nullptr, nullptr, out);
}